// Round 18
// baseline (170.288 us; speedup 1.0000x reference)
//
#include <hip/hip_runtime.h>

#define BATCH 1024
#define SEQ   200
#define EMB   128
#define VOCAB 100000

typedef __attribute__((ext_vector_type(8))) short short8;
typedef __attribute__((ext_vector_type(4))) float f32x4;
typedef _Float16 hh2 __attribute__((ext_vector_type(2)));

__device__ __forceinline__ unsigned short f2bf(float x) {
  unsigned u = __float_as_uint(x);
  u += 0x7fffu + ((u >> 16) & 1u);   // RNE
  return (unsigned short)(u >> 16);
}
__device__ __forceinline__ float bf2f(unsigned short b) {
  return __uint_as_float(((unsigned)b) << 16);
}
__device__ __forceinline__ unsigned int packh2(float a, float b) {
  const hh2 p = (hh2){(_Float16)a, (_Float16)b};
  return __builtin_bit_cast(unsigned int, p);
}
__device__ __forceinline__ float fd(unsigned int h2, unsigned int w2, float acc) {
  return __builtin_amdgcn_fdot2(__builtin_bit_cast(hh2, h2),
                                __builtin_bit_cast(hh2, w2), acc, false);
}

// ---------------------------------------------------------------------------
// cvt_all: one launch does BOTH weight conversions (r17-verified).
// ---------------------------------------------------------------------------
__global__ __launch_bounds__(256) void cvt_all(
    const float* __restrict__ Win, const float* __restrict__ Wh,
    unsigned short* __restrict__ Wb, uint4* __restrict__ W4) {
  const int idx = blockIdx.x * 256 + threadIdx.x;
  if (idx < 16384) {
    Wb[idx] = f2bf(Win[idx]);
  } else {
    const int j = idx - 16384;       // 0..2047
    const int c = j >> 7;
    const int f = j & 127;
    const float* wr = Wh + (size_t)f * EMB;
    uint4 o;
    o.x = packh2(wr[4*c + 0], wr[4*c + 64]);
    o.y = packh2(wr[4*c + 1], wr[4*c + 65]);
    o.z = packh2(wr[4*c + 2], wr[4*c + 66]);
    o.w = packh2(wr[4*c + 3], wr[4*c + 67]);
    W4[j] = o;
  }
}

// ---------------------------------------------------------------------------
// Phase 1: proj3 — register-fixed input projection (single change vs r17).
// proj2 carried bfrag[8][4] = 512B/thread (over the ~132-VGPR allocator cap
// diagnosed in r8-r15) -> B-fragments lived in scratch, reloaded per M-tile.
// proj3: block covers 32 rows (2 M-tiles shared by 4 waves via L1); wave w
// owns f-tiles {w, w+4} = exactly the ipP pairing -> bfrag 2x4 short8 = 32
// VGPRs, total ~80: genuinely resident. 6400 blocks. Same MFMA count, same
// math, same RNE, same pair layout (ipP[r*64+q] = {bf16 ip[r][q], ip[r][q+64]}).
// ---------------------------------------------------------------------------
__global__ __launch_bounds__(256) void proj3(
    const int* __restrict__ xidx, const float* __restrict__ emb,
    const unsigned short* __restrict__ Wb, unsigned int* __restrict__ ipP)
{
  const int tid = threadIdx.x;
  const int w   = tid >> 6;          // 0..3 -> f-tiles {w, w+4}
  const int l   = tid & 63;
  const int l15 = l & 15;
  const int lhi = l >> 4;

  // B fragments for f-tiles nt0 = w, nt1 = w+4 (resident: 32 VGPRs)
  short8 b0[4], b1[4];
#pragma unroll
  for (int kc = 0; kc < 4; ++kc) {
    b0[kc] = *(const short8*)(Wb + (w*16       + l15)*EMB + kc*32 + lhi*8);
    b1[kc] = *(const short8*)(Wb + ((w+4)*16   + l15)*EMB + kc*32 + lhi*8);
  }

  const int rb0 = blockIdx.x * 32;

#pragma unroll
  for (int mt = 0; mt < 2; ++mt) {
    const int rb = rb0 + mt*16;
    const long xe = (long)xidx[rb + l15] * EMB;
    short8 afrag[4];
#pragma unroll
    for (int kc = 0; kc < 4; ++kc) {
      const float4* p = (const float4*)(emb + xe + kc*32 + lhi*8);
      float4 a = p[0], b = p[1];
      short8 fr;
      fr[0]=(short)f2bf(a.x); fr[1]=(short)f2bf(a.y);
      fr[2]=(short)f2bf(a.z); fr[3]=(short)f2bf(a.w);
      fr[4]=(short)f2bf(b.x); fr[5]=(short)f2bf(b.y);
      fr[6]=(short)f2bf(b.z); fr[7]=(short)f2bf(b.w);
      afrag[kc] = fr;
    }
    f32x4 a0 = (f32x4)(0.0f), a1 = (f32x4)(0.0f);
#pragma unroll
    for (int kc = 0; kc < 4; ++kc) {
      a0 = __builtin_amdgcn_mfma_f32_16x16x32_bf16(afrag[kc], b0[kc], a0, 0, 0, 0);
      a1 = __builtin_amdgcn_mfma_f32_16x16x32_bf16(afrag[kc], b1[kc], a1, 0, 0, 0);
    }
    // D layout: row r = rb+lhi*4+j, col f. Tile w -> q = w*16+l15; tile w+4 -> q+64.
#pragma unroll
    for (int j = 0; j < 4; ++j) {
      const unsigned int u = (unsigned)f2bf(a0[j])
                           | ((unsigned)f2bf(a1[j]) << 16);
      ipP[(long)(rb + lhi*4 + j)*64 + w*16 + l15] = u;
    }
  }
}

// ---------------------------------------------------------------------------
// Phase 2: rnn17 verbatim (best measured: 101.5-102 us, VGPR 132).
// Wave-per-row, barrier-free; 2 f/lane; fp16-pair h in LDS double-buffer;
// named-scalar weights + waves_per_eu(1,1).
// ---------------------------------------------------------------------------
__global__ __attribute__((amdgpu_waves_per_eu(1, 1)))
__launch_bounds__(256) void rnn17(
    const unsigned int* __restrict__ ipP, const uint4* __restrict__ W4,
    const float* __restrict__ bin, const float* __restrict__ bh,
    float* __restrict__ out)
{
  __shared__ unsigned int hb[4][2][64];   // [wave][buf][64 h-pair uints]

  const int tid = threadIdx.x;
  const int w   = tid >> 6;            // wave = local row 0..3
  const int l   = tid & 63;
  const int row = blockIdx.x*4 + w;    // global batch row

  hb[w][0][l] = 0u;                    // h_0 = 0

#define WLD(i) \
  const uint4 wa##i = W4[(i)*128 + l]; \
  const uint4 wb##i = W4[(i)*128 + 64 + l];
  WLD(0)  WLD(1)  WLD(2)  WLD(3)  WLD(4)  WLD(5)  WLD(6)  WLD(7)
  WLD(8)  WLD(9)  WLD(10) WLD(11) WLD(12) WLD(13) WLD(14) WLD(15)
#undef WLD

  const float bias0 = bin[l]      + bh[l];
  const float bias1 = bin[l + 64] + bh[l + 64];
  __syncthreads();   // h0 visible (and weight loads drained once)

  const unsigned int* ipp = ipP + (size_t)row * SEQ * 64 + l;
  unsigned int ic = ipp[0];
  unsigned int in = ipp[64];

  float hf0 = 0.0f, hf1 = 0.0f;

  for (int s = 0; s < SEQ; ++s) {
    const int sp = (s + 2 < SEQ) ? s + 2 : SEQ - 1;
    const unsigned int pn = ipp[(size_t)sp * 64];

    const uint4* th = (const uint4*)&hb[w][s & 1][0];

    float a00 = bias0 + __uint_as_float(ic << 16);
    float a10 = bias1 + __uint_as_float(ic & 0xffff0000u);
    float a01 = 0.0f, a02 = 0.0f, a03 = 0.0f;
    float a11 = 0.0f, a12 = 0.0f, a13 = 0.0f;

#define STEP(i, K) { \
    const uint4 hc = th[i]; \
    a0##K = fd(hc.x, wa##i.x, a0##K); \
    a0##K = fd(hc.y, wa##i.y, a0##K); \
    a0##K = fd(hc.z, wa##i.z, a0##K); \
    a0##K = fd(hc.w, wa##i.w, a0##K); \
    a1##K = fd(hc.x, wb##i.x, a1##K); \
    a1##K = fd(hc.y, wb##i.y, a1##K); \
    a1##K = fd(hc.z, wb##i.z, a1##K); \
    a1##K = fd(hc.w, wb##i.w, a1##K); }
    STEP(0,0)  STEP(1,1)  STEP(2,2)  STEP(3,3)
    STEP(4,0)  STEP(5,1)  STEP(6,2)  STEP(7,3)
    STEP(8,0)  STEP(9,1)  STEP(10,2) STEP(11,3)
    STEP(12,0) STEP(13,1) STEP(14,2) STEP(15,3)
#undef STEP

    const float v0 = (a00 + a01) + (a02 + a03);
    const float v1 = (a10 + a11) + (a12 + a13);

    const float e0 = __expf(2.0f * v0);
    hf0 = 1.0f - __fdividef(2.0f, e0 + 1.0f);
    const float e1 = __expf(2.0f * v1);
    hf1 = 1.0f - __fdividef(2.0f, e1 + 1.0f);

    hb[w][(s + 1) & 1][l] = packh2(hf0, hf1);

    ic = in;
    in = pn;
  }

  float pj = hf0*hf0 + hf1*hf1;
#pragma unroll
  for (int off = 1; off < 64; off <<= 1) pj += __shfl_xor(pj, off, 64);
  const float inv = 1.0f / fmaxf(sqrtf(pj), 1e-12f);
  out[(size_t)row*EMB + l]      = hf0 * inv;
  out[(size_t)row*EMB + 64 + l] = hf1 * inv;
}

// ---------------------------------------------------------------------------
// Fallback (small ws): round-1 VALU recurrence (known-correct, no scratch).
// ---------------------------------------------------------------------------
__global__ __launch_bounds__(512) void rnn_fused(
    const int* __restrict__ xidx, const float* __restrict__ emb,
    const float* __restrict__ Win, const float* __restrict__ bin,
    const float* __restrict__ Wh,  const float* __restrict__ bh,
    float* __restrict__ out)
{
  __shared__ float h_lds[4][EMB];
  __shared__ float part[8][4][EMB];
  __shared__ float emb_lds[2][4][EMB];
  __shared__ int   x_lds[4][SEQ];
  __shared__ float red[8];

  const int t   = threadIdx.x;
  const int f0  = (t & 63) * 2;
  const int eg  = t >> 6;
  const int e0  = eg * 16;
  const int b0  = blockIdx.x * 4;
  const int row = t >> 7;
  const int ff  = t & 127;

  float wh0[16], wh1[16], wi0[16], wi1[16];
  {
    const float* p0 = Wh + f0*EMB + e0;
    const float* p1 = Wh + (f0+1)*EMB + e0;
    const float* q0 = Win + f0*EMB + e0;
    const float* q1 = Win + (f0+1)*EMB + e0;
#pragma unroll
    for (int q = 0; q < 4; ++q) {
      float4 a = ((const float4*)p0)[q];
      wh0[4*q+0]=a.x; wh0[4*q+1]=a.y; wh0[4*q+2]=a.z; wh0[4*q+3]=a.w;
      float4 b = ((const float4*)p1)[q];
      wh1[4*q+0]=b.x; wh1[4*q+1]=b.y; wh1[4*q+2]=b.z; wh1[4*q+3]=b.w;
      float4 c = ((const float4*)q0)[q];
      wi0[4*q+0]=c.x; wi0[4*q+1]=c.y; wi0[4*q+2]=c.z; wi0[4*q+3]=c.w;
      float4 d = ((const float4*)q1)[q];
      wi1[4*q+0]=d.x; wi1[4*q+1]=d.y; wi1[4*q+2]=d.z; wi1[4*q+3]=d.w;
    }
  }
  const float bc = bin[ff] + bh[ff];
  h_lds[row][ff] = 0.0f;
  for (int i = t; i < 4*SEQ; i += 512)
    x_lds[i / SEQ][i % SEQ] = xidx[(b0 + i/SEQ)*SEQ + (i % SEQ)];
  __syncthreads();
  emb_lds[0][row][ff] = emb[(long)x_lds[row][0]*EMB + ff];
  __syncthreads();

  int cur = 0;
  for (int s = 0; s < SEQ; ++s) {
    float nxt = 0.0f;
    if (s + 1 < SEQ) nxt = emb[(long)x_lds[row][s+1]*EMB + ff];
    float pa0[4], pa1[4];
#pragma unroll
    for (int rq = 0; rq < 4; ++rq) { pa0[rq] = 0.0f; pa1[rq] = 0.0f; }
#pragma unroll
    for (int rq = 0; rq < 4; ++rq) {
      const float4* hp  = (const float4*)&h_lds[rq][e0];
      const float4* epv = (const float4*)&emb_lds[cur][rq][e0];
#pragma unroll
      for (int q = 0; q < 4; ++q) {
        float4 hv = hp[q], ev = epv[q];
        pa0[rq] = fmaf(hv.x, wh0[4*q+0], pa0[rq]); pa0[rq] = fmaf(hv.y, wh0[4*q+1], pa0[rq]);
        pa0[rq] = fmaf(hv.z, wh0[4*q+2], pa0[rq]); pa0[rq] = fmaf(hv.w, wh0[4*q+3], pa0[rq]);
        pa1[rq] = fmaf(hv.x, wh1[4*q+0], pa1[rq]); pa1[rq] = fmaf(hv.y, wh1[4*q+1], pa1[rq]);
        pa1[rq] = fmaf(hv.z, wh1[4*q+2], pa1[rq]); pa1[rq] = fmaf(hv.w, wh1[4*q+3], pa1[rq]);
        pa0[rq] = fmaf(ev.x, wi0[4*q+0], pa0[rq]); pa0[rq] = fmaf(ev.y, wi0[4*q+1], pa0[rq]);
        pa0[rq] = fmaf(ev.z, wi0[4*q+2], pa0[rq]); pa0[rq] = fmaf(ev.w, wi0[4*q+3], pa0[rq]);
        pa1[rq] = fmaf(ev.x, wi1[4*q+0], pa1[rq]); pa1[rq] = fmaf(ev.y, wi1[4*q+1], pa1[rq]);
        pa1[rq] = fmaf(ev.z, wi1[4*q+2], pa1[rq]); pa1[rq] = fmaf(ev.w, wi1[4*q+3], pa1[rq]);
      }
    }
#pragma unroll
    for (int rq = 0; rq < 4; ++rq) {
      part[eg][rq][f0]   = pa0[rq];
      part[eg][rq][f0+1] = pa1[rq];
    }
    __syncthreads();
    float acc = bc;
#pragma unroll
    for (int g = 0; g < 8; ++g) acc += part[g][row][ff];
    float hn = tanhf(acc);
    if (s + 1 < SEQ) emb_lds[cur ^ 1][row][ff] = nxt;
    h_lds[row][ff] = hn;
    __syncthreads();
    cur ^= 1;
  }
  float hv = h_lds[row][ff];
  float sq = hv * hv;
#pragma unroll
  for (int off = 32; off > 0; off >>= 1) sq += __shfl_xor(sq, off, 64);
  if ((t & 63) == 0) red[t >> 6] = sq;
  __syncthreads();
  float nrm = sqrtf(red[row*2] + red[row*2 + 1]);
  out[(b0 + row)*EMB + ff] = hv / fmaxf(nrm, 1e-12f);
}

// ---------------------------------------------------------------------------
extern "C" void kernel_launch(void* const* d_in, const int* in_sizes, int n_in,
                              void* d_out, int out_size, void* d_ws, size_t ws_size,
                              hipStream_t stream) {
  const int*   x    = (const int*)  d_in[0];
  const float* emb  = (const float*)d_in[1];
  const float* Win  = (const float*)d_in[2];
  const float* bin  = (const float*)d_in[3];
  const float* Wh   = (const float*)d_in[4];
  const float* bh   = (const float*)d_in[5];
  float* out = (float*)d_out;

  const size_t ip_bytes = (size_t)BATCH * SEQ * 64 * sizeof(unsigned int); // 52.4 MB
  const size_t wb_bytes = (size_t)EMB * EMB * sizeof(unsigned short);      // 32 KB
  const size_t w4_bytes = (size_t)16 * 128 * sizeof(uint4);                // 32 KB
  const size_t need     = ip_bytes + wb_bytes + w4_bytes;
  if (ws_size >= need) {
    unsigned int*   ipP = (unsigned int*)d_ws;
    unsigned short* Wb  = (unsigned short*)((char*)d_ws + ip_bytes);
    uint4*          W4  = (uint4*)((char*)d_ws + ip_bytes + wb_bytes);
    cvt_all<<<72, 256, 0, stream>>>(Win, Wh, Wb, W4);
    proj3<<<(BATCH*SEQ)/32, 256, 0, stream>>>(x, emb, Wb, ipP);
    rnn17<<<BATCH/4, 256, 0, stream>>>(ipP, W4, bin, bh, out);
  } else {
    rnn_fused<<<BATCH/4, 512, 0, stream>>>(x, emb, Win, bin, Wh, bh, out);
  }
}

// Round 20
// 131.532 us; speedup vs baseline: 1.2946x; 1.2946x over previous
//
#include <hip/hip_runtime.h>

#define BATCH 1024
#define SEQ   200
#define EMB   128
#define VOCAB 100000

typedef __attribute__((ext_vector_type(8))) short short8;
typedef __attribute__((ext_vector_type(4))) float f32x4;
typedef _Float16 hh2 __attribute__((ext_vector_type(2)));

__device__ __forceinline__ unsigned short f2bf(float x) {
  unsigned u = __float_as_uint(x);
  u += 0x7fffu + ((u >> 16) & 1u);   // RNE
  return (unsigned short)(u >> 16);
}
__device__ __forceinline__ float bf2f(unsigned short b) {
  return __uint_as_float(((unsigned)b) << 16);
}
__device__ __forceinline__ unsigned int packh2(float a, float b) {
  const hh2 p = (hh2){(_Float16)a, (_Float16)b};
  return __builtin_bit_cast(unsigned int, p);
}
__device__ __forceinline__ float fd(unsigned int h2, unsigned int w2, float acc) {
  return __builtin_amdgcn_fdot2(__builtin_bit_cast(hh2, h2),
                                __builtin_bit_cast(hh2, w2), acc, false);
}
__device__ __forceinline__ short8 cvt8(float4 a, float4 b) {
  short8 fr;
  fr[0]=(short)f2bf(a.x); fr[1]=(short)f2bf(a.y);
  fr[2]=(short)f2bf(a.z); fr[3]=(short)f2bf(a.w);
  fr[4]=(short)f2bf(b.x); fr[5]=(short)f2bf(b.y);
  fr[6]=(short)f2bf(b.z); fr[7]=(short)f2bf(b.w);
  return fr;
}

// ---------------------------------------------------------------------------
// cvt_all: one launch does BOTH weight conversions (r17-verified).
// ---------------------------------------------------------------------------
__global__ __launch_bounds__(256) void cvt_all(
    const float* __restrict__ Win, const float* __restrict__ Wh,
    unsigned short* __restrict__ Wb, uint4* __restrict__ W4) {
  const int idx = blockIdx.x * 256 + threadIdx.x;
  if (idx < 16384) {
    Wb[idx] = f2bf(Win[idx]);
  } else {
    const int j = idx - 16384;       // 0..2047
    const int c = j >> 7;
    const int f = j & 127;
    const float* wr = Wh + (size_t)f * EMB;
    uint4 o;
    o.x = packh2(wr[4*c + 0], wr[4*c + 64]);
    o.y = packh2(wr[4*c + 1], wr[4*c + 65]);
    o.z = packh2(wr[4*c + 2], wr[4*c + 66]);
    o.w = packh2(wr[4*c + 3], wr[4*c + 67]);
    W4[j] = o;
  }
}

// ---------------------------------------------------------------------------
// Phase 1: proj4 (FIXED) — LDS-shared-A input projection.
// r19 NaN post-mortem: the A-staging loop wrote only 4 of 8 chunks per
// half-row (q<4 instead of q<8) — half of A_lds uninitialized. Fixed: each
// thread converts its full 64-float half (8 x short8 chunks).
// Design (r18 theory, unchanged): block = 128 rows; A gathered+converted
// ONCE into 32KB swizzled LDS; wave w computes f-tiles {w, w+4} for all
// 8 M-tiles; B = 8 named short8 = 32 VGPRs, resident. Fragment/D layouts
// and ipP pairing identical to verified proj2/proj3.
// ---------------------------------------------------------------------------
__global__ __launch_bounds__(256) void proj4(
    const int* __restrict__ xidx, const float* __restrict__ emb,
    const unsigned short* __restrict__ Wb, unsigned int* __restrict__ ipP)
{
  __shared__ char A_lds[8 * 4096];   // [tile][16 rows][256B bf16], swizzled

  const int tid = threadIdx.x;
  const int w   = tid >> 6;          // wave -> f-tiles {w, w+4}
  const int l   = tid & 63;
  const int l15 = l & 15;
  const int lhi = l >> 4;

  // B fragments (named, resident): tiles w and w+4
#define BLD(k) \
  const short8 b0##k = *(const short8*)(Wb + (w*16     + l15)*EMB + (k)*32 + lhi*8); \
  const short8 b1##k = *(const short8*)(Wb + ((w+4)*16 + l15)*EMB + (k)*32 + lhi*8);
  BLD(0) BLD(1) BLD(2) BLD(3)
#undef BLD

  const int rb0 = blockIdx.x * 128;

  // Stage A: thread t -> row ri = t>>1 (0..127), half hf = t&1 (64 floats
  // = 128 bytes = 8 chunks). Chunk (hf*8+q) stored at byte ^((ri&7)<<4).
  {
    const int ri = tid >> 1, hf = tid & 1;
    const long xe = (long)xidx[rb0 + ri] * EMB + hf*64;
    const float4* src = (const float4*)(emb + xe);
    char* dst = A_lds + (ri >> 4)*4096 + (ri & 15)*256;
    const int rs = ((ri & 7) << 4);
#pragma unroll
    for (int q = 0; q < 8; ++q) {
      const short8 fr = cvt8(src[2*q], src[2*q + 1]);
      *(short8*)(dst + ((hf*128 + q*16) ^ rs)) = fr;
    }
  }
  __syncthreads();

  // Compute: 8 M-tiles x (4 swizzled ds_read_b128 + 8 MFMA + 4 pair-stores)
  const int rswz = ((l15 & 7) << 4);
#pragma unroll
  for (int mt = 0; mt < 8; ++mt) {
    const char* tb = A_lds + mt*4096 + l15*256;
    const short8 af0 = *(const short8*)(tb + ((0*64 + lhi*16) ^ rswz));
    const short8 af1 = *(const short8*)(tb + ((1*64 + lhi*16) ^ rswz));
    const short8 af2 = *(const short8*)(tb + ((2*64 + lhi*16) ^ rswz));
    const short8 af3 = *(const short8*)(tb + ((3*64 + lhi*16) ^ rswz));
    f32x4 a0 = (f32x4)(0.0f), a1 = (f32x4)(0.0f);
    a0 = __builtin_amdgcn_mfma_f32_16x16x32_bf16(af0, b00, a0, 0, 0, 0);
    a1 = __builtin_amdgcn_mfma_f32_16x16x32_bf16(af0, b10, a1, 0, 0, 0);
    a0 = __builtin_amdgcn_mfma_f32_16x16x32_bf16(af1, b01, a0, 0, 0, 0);
    a1 = __builtin_amdgcn_mfma_f32_16x16x32_bf16(af1, b11, a1, 0, 0, 0);
    a0 = __builtin_amdgcn_mfma_f32_16x16x32_bf16(af2, b02, a0, 0, 0, 0);
    a1 = __builtin_amdgcn_mfma_f32_16x16x32_bf16(af2, b12, a1, 0, 0, 0);
    a0 = __builtin_amdgcn_mfma_f32_16x16x32_bf16(af3, b03, a0, 0, 0, 0);
    a1 = __builtin_amdgcn_mfma_f32_16x16x32_bf16(af3, b13, a1, 0, 0, 0);
    // D: row = rb0 + mt*16 + lhi*4 + j, pair q = w*16+l15 (f) with f+64
#pragma unroll
    for (int j = 0; j < 4; ++j) {
      const unsigned int u = (unsigned)f2bf(a0[j])
                           | ((unsigned)f2bf(a1[j]) << 16);
      ipP[(long)(rb0 + mt*16 + lhi*4 + j)*64 + w*16 + l15] = u;
    }
  }
}

// ---------------------------------------------------------------------------
// Phase 2: rnn17 verbatim (best measured: 101.3-102 us, VGPR 132).
// ---------------------------------------------------------------------------
__global__ __attribute__((amdgpu_waves_per_eu(1, 1)))
__launch_bounds__(256) void rnn17(
    const unsigned int* __restrict__ ipP, const uint4* __restrict__ W4,
    const float* __restrict__ bin, const float* __restrict__ bh,
    float* __restrict__ out)
{
  __shared__ unsigned int hb[4][2][64];   // [wave][buf][64 h-pair uints]

  const int tid = threadIdx.x;
  const int w   = tid >> 6;            // wave = local row 0..3
  const int l   = tid & 63;
  const int row = blockIdx.x*4 + w;    // global batch row

  hb[w][0][l] = 0u;                    // h_0 = 0

#define WLD(i) \
  const uint4 wa##i = W4[(i)*128 + l]; \
  const uint4 wb##i = W4[(i)*128 + 64 + l];
  WLD(0)  WLD(1)  WLD(2)  WLD(3)  WLD(4)  WLD(5)  WLD(6)  WLD(7)
  WLD(8)  WLD(9)  WLD(10) WLD(11) WLD(12) WLD(13) WLD(14) WLD(15)
#undef WLD

  const float bias0 = bin[l]      + bh[l];
  const float bias1 = bin[l + 64] + bh[l + 64];
  __syncthreads();   // h0 visible (and weight loads drained once)

  const unsigned int* ipp = ipP + (size_t)row * SEQ * 64 + l;
  unsigned int ic = ipp[0];
  unsigned int in = ipp[64];

  float hf0 = 0.0f, hf1 = 0.0f;

  for (int s = 0; s < SEQ; ++s) {
    const int sp = (s + 2 < SEQ) ? s + 2 : SEQ - 1;
    const unsigned int pn = ipp[(size_t)sp * 64];

    const uint4* th = (const uint4*)&hb[w][s & 1][0];

    float a00 = bias0 + __uint_as_float(ic << 16);
    float a10 = bias1 + __uint_as_float(ic & 0xffff0000u);
    float a01 = 0.0f, a02 = 0.0f, a03 = 0.0f;
    float a11 = 0.0f, a12 = 0.0f, a13 = 0.0f;

#define STEP(i, K) { \
    const uint4 hc = th[i]; \
    a0##K = fd(hc.x, wa##i.x, a0##K); \
    a0##K = fd(hc.y, wa##i.y, a0##K); \
    a0##K = fd(hc.z, wa##i.z, a0##K); \
    a0##K = fd(hc.w, wa##i.w, a0##K); \
    a1##K = fd(hc.x, wb##i.x, a1##K); \
    a1##K = fd(hc.y, wb##i.y, a1##K); \
    a1##K = fd(hc.z, wb##i.z, a1##K); \
    a1##K = fd(hc.w, wb##i.w, a1##K); }
    STEP(0,0)  STEP(1,1)  STEP(2,2)  STEP(3,3)
    STEP(4,0)  STEP(5,1)  STEP(6,2)  STEP(7,3)
    STEP(8,0)  STEP(9,1)  STEP(10,2) STEP(11,3)
    STEP(12,0) STEP(13,1) STEP(14,2) STEP(15,3)
#undef STEP

    const float v0 = (a00 + a01) + (a02 + a03);
    const float v1 = (a10 + a11) + (a12 + a13);

    const float e0 = __expf(2.0f * v0);
    hf0 = 1.0f - __fdividef(2.0f, e0 + 1.0f);
    const float e1 = __expf(2.0f * v1);
    hf1 = 1.0f - __fdividef(2.0f, e1 + 1.0f);

    hb[w][(s + 1) & 1][l] = packh2(hf0, hf1);

    ic = in;
    in = pn;
  }

  float pj = hf0*hf0 + hf1*hf1;
#pragma unroll
  for (int off = 1; off < 64; off <<= 1) pj += __shfl_xor(pj, off, 64);
  const float inv = 1.0f / fmaxf(sqrtf(pj), 1e-12f);
  out[(size_t)row*EMB + l]      = hf0 * inv;
  out[(size_t)row*EMB + 64 + l] = hf1 * inv;
}

// ---------------------------------------------------------------------------
// Fallback (small ws): round-1 VALU recurrence (known-correct, no scratch).
// ---------------------------------------------------------------------------
__global__ __launch_bounds__(512) void rnn_fused(
    const int* __restrict__ xidx, const float* __restrict__ emb,
    const float* __restrict__ Win, const float* __restrict__ bin,
    const float* __restrict__ Wh,  const float* __restrict__ bh,
    float* __restrict__ out)
{
  __shared__ float h_lds[4][EMB];
  __shared__ float part[8][4][EMB];
  __shared__ float emb_lds[2][4][EMB];
  __shared__ int   x_lds[4][SEQ];
  __shared__ float red[8];

  const int t   = threadIdx.x;
  const int f0  = (t & 63) * 2;
  const int eg  = t >> 6;
  const int e0  = eg * 16;
  const int b0  = blockIdx.x * 4;
  const int row = t >> 7;
  const int ff  = t & 127;

  float wh0[16], wh1[16], wi0[16], wi1[16];
  {
    const float* p0 = Wh + f0*EMB + e0;
    const float* p1 = Wh + (f0+1)*EMB + e0;
    const float* q0 = Win + f0*EMB + e0;
    const float* q1 = Win + (f0+1)*EMB + e0;
#pragma unroll
    for (int q = 0; q < 4; ++q) {
      float4 a = ((const float4*)p0)[q];
      wh0[4*q+0]=a.x; wh0[4*q+1]=a.y; wh0[4*q+2]=a.z; wh0[4*q+3]=a.w;
      float4 b = ((const float4*)p1)[q];
      wh1[4*q+0]=b.x; wh1[4*q+1]=b.y; wh1[4*q+2]=b.z; wh1[4*q+3]=b.w;
      float4 c = ((const float4*)q0)[q];
      wi0[4*q+0]=c.x; wi0[4*q+1]=c.y; wi0[4*q+2]=c.z; wi0[4*q+3]=c.w;
      float4 d = ((const float4*)q1)[q];
      wi1[4*q+0]=d.x; wi1[4*q+1]=d.y; wi1[4*q+2]=d.z; wi1[4*q+3]=d.w;
    }
  }
  const float bc = bin[ff] + bh[ff];
  h_lds[row][ff] = 0.0f;
  for (int i = t; i < 4*SEQ; i += 512)
    x_lds[i / SEQ][i % SEQ] = xidx[(b0 + i/SEQ)*SEQ + (i % SEQ)];
  __syncthreads();
  emb_lds[0][row][ff] = emb[(long)x_lds[row][0]*EMB + ff];
  __syncthreads();

  int cur = 0;
  for (int s = 0; s < SEQ; ++s) {
    float nxt = 0.0f;
    if (s + 1 < SEQ) nxt = emb[(long)x_lds[row][s+1]*EMB + ff];
    float pa0[4], pa1[4];
#pragma unroll
    for (int rq = 0; rq < 4; ++rq) { pa0[rq] = 0.0f; pa1[rq] = 0.0f; }
#pragma unroll
    for (int rq = 0; rq < 4; ++rq) {
      const float4* hp  = (const float4*)&h_lds[rq][e0];
      const float4* epv = (const float4*)&emb_lds[cur][rq][e0];
#pragma unroll
      for (int q = 0; q < 4; ++q) {
        float4 hv = hp[q], ev = epv[q];
        pa0[rq] = fmaf(hv.x, wh0[4*q+0], pa0[rq]); pa0[rq] = fmaf(hv.y, wh0[4*q+1], pa0[rq]);
        pa0[rq] = fmaf(hv.z, wh0[4*q+2], pa0[rq]); pa0[rq] = fmaf(hv.w, wh0[4*q+3], pa0[rq]);
        pa1[rq] = fmaf(hv.x, wh1[4*q+0], pa1[rq]); pa1[rq] = fmaf(hv.y, wh1[4*q+1], pa1[rq]);
        pa1[rq] = fmaf(hv.z, wh1[4*q+2], pa1[rq]); pa1[rq] = fmaf(hv.w, wh1[4*q+3], pa1[rq]);
        pa0[rq] = fmaf(ev.x, wi0[4*q+0], pa0[rq]); pa0[rq] = fmaf(ev.y, wi0[4*q+1], pa0[rq]);
        pa0[rq] = fmaf(ev.z, wi0[4*q+2], pa0[rq]); pa0[rq] = fmaf(ev.w, wi0[4*q+3], pa0[rq]);
        pa1[rq] = fmaf(ev.x, wi1[4*q+0], pa1[rq]); pa1[rq] = fmaf(ev.y, wi1[4*q+1], pa1[rq]);
        pa1[rq] = fmaf(ev.z, wi1[4*q+2], pa1[rq]); pa1[rq] = fmaf(ev.w, wi1[4*q+3], pa1[rq]);
      }
    }
#pragma unroll
    for (int rq = 0; rq < 4; ++rq) {
      part[eg][rq][f0]   = pa0[rq];
      part[eg][rq][f0+1] = pa1[rq];
    }
    __syncthreads();
    float acc = bc;
#pragma unroll
    for (int g = 0; g < 8; ++g) acc += part[g][row][ff];
    float hn = tanhf(acc);
    if (s + 1 < SEQ) emb_lds[cur ^ 1][row][ff] = nxt;
    h_lds[row][ff] = hn;
    __syncthreads();
    cur ^= 1;
  }
  float hv = h_lds[row][ff];
  float sq = hv * hv;
#pragma unroll
  for (int off = 32; off > 0; off >>= 1) sq += __shfl_xor(sq, off, 64);
  if ((t & 63) == 0) red[t >> 6] = sq;
  __syncthreads();
  float nrm = sqrtf(red[row*2] + red[row*2 + 1]);
  out[(b0 + row)*EMB + ff] = hv / fmaxf(nrm, 1e-12f);
}

// ---------------------------------------------------------------------------
extern "C" void kernel_launch(void* const* d_in, const int* in_sizes, int n_in,
                              void* d_out, int out_size, void* d_ws, size_t ws_size,
                              hipStream_t stream) {
  const int*   x    = (const int*)  d_in[0];
  const float* emb  = (const float*)d_in[1];
  const float* Win  = (const float*)d_in[2];
  const float* bin  = (const float*)d_in[3];
  const float* Wh   = (const float*)d_in[4];
  const float* bh   = (const float*)d_in[5];
  float* out = (float*)d_out;

  const size_t ip_bytes = (size_t)BATCH * SEQ * 64 * sizeof(unsigned int); // 52.4 MB
  const size_t wb_bytes = (size_t)EMB * EMB * sizeof(unsigned short);      // 32 KB
  const size_t w4_bytes = (size_t)16 * 128 * sizeof(uint4);                // 32 KB
  const size_t need     = ip_bytes + wb_bytes + w4_bytes;
  if (ws_size >= need) {
    unsigned int*   ipP = (unsigned int*)d_ws;
    unsigned short* Wb  = (unsigned short*)((char*)d_ws + ip_bytes);
    uint4*          W4  = (uint4*)((char*)d_ws + ip_bytes + wb_bytes);
    cvt_all<<<72, 256, 0, stream>>>(Win, Wh, Wb, W4);
    proj4<<<(BATCH*SEQ)/128, 256, 0, stream>>>(x, emb, Wb, ipP);
    rnn17<<<BATCH/4, 256, 0, stream>>>(ipP, W4, bin, bh, out);
  } else {
    rnn_fused<<<BATCH/4, 512, 0, stream>>>(x, emb, Win, bin, Wh, bh, out);
  }
}